// Round 7
// baseline (180.954 us; speedup 1.0000x reference)
//
#include <hip/hip_runtime.h>
#include <stdint.h>

// ---------------------------------------------------------------------------
// RLMALinear: out = x @ (alpha*R + U@V)^T + bias
//   x: [32,4096,512] f32, U: [512,64] f32, V: [64,512] f32, bias: [512] f32
// Stage 1: build W (bf16) in d_ws via threefry2x32 + erfinv.
// Stage 2: block = 128 m-rows x ALL 512 n-cols, K-tiled by 32.
//   x staged f32 + W staged bf16 via global_load_lds, 16B-granule XOR swizzle
//   both sides. R6: TRIPLE-buffered staging with counted vmcnt(6) + raw
//   s_barrier (T3+T4): 2 tiles always in flight, never drain to 0 in-loop.
//   acc[4][8] f32x4 = 128 VGPR statically indexed. x read from HBM once.
// ---------------------------------------------------------------------------

#define M_TOTAL 131072
#define N_DIM 512
#define K_DIM 512
#define RANK 64

#define BM 128
#define BK 32
#define NKT (K_DIM / BK)  // 16

// LDS (bytes): A bufs 3x16KB @ 0; W bufs 3x32KB @ 49152. Total 147456.
#define AOFF(b) ((b)*16384)
#define WOFF(b) (49152 + (b)*32768)

typedef __attribute__((ext_vector_type(8))) short bf16x8;
typedef __attribute__((ext_vector_type(4))) float f32x4;

// ---- JAX threefry2x32 -----------------------------------------------------
__device__ __forceinline__ void threefry2x32(uint32_t k0, uint32_t k1,
                                             uint32_t x0, uint32_t x1,
                                             uint32_t& y0, uint32_t& y1) {
  uint32_t ks2 = k0 ^ k1 ^ 0x1BD11BDAu;
  const uint32_t ks[3] = {k0, k1, ks2};
  const int R0[4] = {13, 15, 26, 6};
  const int R1[4] = {17, 29, 16, 24};
  x0 += ks[0];
  x1 += ks[1];
#pragma unroll
  for (int g = 0; g < 5; ++g) {
    const int* r = (g & 1) ? R1 : R0;
#pragma unroll
    for (int i = 0; i < 4; ++i) {
      x0 += x1;
      x1 = (x1 << r[i]) | (x1 >> (32 - r[i]));
      x1 ^= x0;
    }
    x0 += ks[(g + 1) % 3];
    x1 += ks[(g + 2) % 3] + (uint32_t)(g + 1);
  }
  y0 = x0;
  y1 = x1;
}

// ---- XLA ErfInv32 (Giles 2012) --------------------------------------------
__device__ __forceinline__ float erfinv_f32(float x) {
  float w = -log1pf(-x * x);
  float p;
  if (w < 5.0f) {
    w = w - 2.5f;
    p = 2.81022636e-08f;
    p = fmaf(p, w, 3.43273939e-07f);
    p = fmaf(p, w, -3.5233877e-06f);
    p = fmaf(p, w, -4.39150654e-06f);
    p = fmaf(p, w, 0.00021858087f);
    p = fmaf(p, w, -0.00125372503f);
    p = fmaf(p, w, -0.00417768164f);
    p = fmaf(p, w, 0.246640727f);
    p = fmaf(p, w, 1.50140941f);
  } else {
    w = sqrtf(w) - 3.0f;
    p = -0.000200214257f;
    p = fmaf(p, w, 0.000100950558f);
    p = fmaf(p, w, 0.00134934322f);
    p = fmaf(p, w, -0.00367342844f);
    p = fmaf(p, w, 0.00573950773f);
    p = fmaf(p, w, -0.0076224613f);
    p = fmaf(p, w, 0.00943887047f);
    p = fmaf(p, w, 1.00167406f);
    p = fmaf(p, w, 2.83297682f);
  }
  return p * x;
}

__device__ __forceinline__ unsigned short f32_to_bf16_rtne(float f) {
  uint32_t x = __float_as_uint(f);
  uint32_t r = (x + 0x7FFFu + ((x >> 16) & 1u)) >> 16;
  return (unsigned short)r;
}

// ---- Stage 1 --------------------------------------------------------------
__global__ __launch_bounds__(256) void build_w_kernel(
    const float* __restrict__ alpha_p, const float* __restrict__ U,
    const float* __restrict__ V, const int* __restrict__ k_iter_p,
    unsigned short* __restrict__ Wb) {
  int idx = blockIdx.x * blockDim.x + threadIdx.x;
  uint32_t s = (1234u ^ (uint32_t)(*k_iter_p));
  uint32_t y0, y1;
  threefry2x32(0u, s, 0u, (uint32_t)idx, y0, y1);
  uint32_t bits = y0 ^ y1;
  float u01 = __uint_as_float((bits >> 9) | 0x3f800000u) - 1.0f;
  const float lo = -0.99999994f;
  float u = fmaxf(lo, u01 * 2.0f + lo);
  float rnorm = 1.41421354f * erfinv_f32(u);
  const float scale = 0.044194173824159216f;  // fp32(1/sqrt(512))

  int o = idx >> 9;
  int i = idx & 511;
  float uv = 0.0f;
#pragma unroll 8
  for (int r = 0; r < RANK; ++r)
    uv = fmaf(U[o * RANK + r], V[r * N_DIM + i], uv);

  float w = (*alpha_p) * (rnorm * scale) + uv;
  Wb[idx] = f32_to_bf16_rtne(w);
}

// ---- async 16B global->LDS ------------------------------------------------
__device__ __forceinline__ void gload16(const void* g, void* l) {
  __builtin_amdgcn_global_load_lds(
      (const __attribute__((address_space(1))) void*)g,
      (__attribute__((address_space(3))) void*)l, 16, 0, 0);
}

__device__ __forceinline__ bf16x8 cvt8(const float4& lo, const float4& hi) {
  union {
    bf16x8 v;
    uint32_t d[4];
  } au;
  asm("v_cvt_pk_bf16_f32 %0, %1, %2" : "=v"(au.d[0]) : "v"(lo.x), "v"(lo.y));
  asm("v_cvt_pk_bf16_f32 %0, %1, %2" : "=v"(au.d[1]) : "v"(lo.z), "v"(lo.w));
  asm("v_cvt_pk_bf16_f32 %0, %1, %2" : "=v"(au.d[2]) : "v"(hi.x), "v"(hi.y));
  asm("v_cvt_pk_bf16_f32 %0, %1, %2" : "=v"(au.d[3]) : "v"(hi.z), "v"(hi.w));
  return au.v;
}

// ---- Stage 2: GEMM --------------------------------------------------------
__global__ __launch_bounds__(512, 2) void gemm_kernel(
    const float* __restrict__ X, const unsigned short* __restrict__ Wb,
    const float* __restrict__ bias, float* __restrict__ Out) {
  extern __shared__ char smem[];

  const int tid = threadIdx.x;
  const int lane = tid & 63;
  const int wave = tid >> 6;  // 8 waves: 2m x 4n
  const int wm = wave >> 2;   // 0..1: 64 m-rows each
  const int wn = wave & 3;    // 0..3: 128 n-cols each
  const size_t m0 = (size_t)blockIdx.x * BM;

  // ---- staging address precompute (thread-constant, tile 0) ----
  // A tile: 1024 slots of 16B (row = slot>>3, q = slot&7), 2 calls/thread.
  //   LDS(row,q) holds X granule (q ^ ((row&3)<<1)) of the 32-f32 K-window.
  // W slab: 2048 slots (row = slot>>2, q = slot&3), 4 calls/thread.
  //   LDS(row,q) holds W granule (q ^ (row&3)) of the 32-bf16 K-window.
  const char* pA[2];
#pragma unroll
  for (int c = 0; c < 2; ++c) {
    int slot = c * 512 + tid;
    int row = slot >> 3, q = slot & 7;
    int gcol = (q ^ ((row & 3) << 1)) * 4;  // f32 units
    pA[c] = (const char*)(X + (m0 + row) * K_DIM + gcol);
  }
  const char* pW[4];
#pragma unroll
  for (int c = 0; c < 4; ++c) {
    int slot = c * 512 + tid;
    int row = slot >> 2, q = slot & 3;
    int gcol = (q ^ (row & 3)) * 8;  // bf16 units
    pW[c] = (const char*)(Wb + (size_t)row * K_DIM + gcol);
  }
  const int ldsA_base = wave * 1024;  // + c*8192 (wave-uniform dest)
  const int ldsW_base = wave * 1024;

  // K-step kt_: A advances 128 B/step (32 f32), W advances 64 B/step (32 bf16)
#define STAGE(buf_, kt_)                                                     \
  {                                                                          \
    _Pragma("unroll") for (int c = 0; c < 2; ++c)                            \
        gload16(pA[c] + (kt_)*128, smem + AOFF(buf_) + c * 8192 + ldsA_base);\
    _Pragma("unroll") for (int c = 0; c < 4; ++c)                            \
        gload16(pW[c] + (kt_)*64, smem + WOFF(buf_) + c * 8192 + ldsW_base); \
  }

  // ---- fragment-read LDS offsets (thread-constant, exclude buffer base) ----
  const int r = lane & 15;
  const int g = lane >> 4;
  int offA[4];  // x-frag i: row = wm*64+i*16+r, granule pair (2g)^((r&3)<<1)
#pragma unroll
  for (int i = 0; i < 4; ++i) {
    int row = wm * 64 + i * 16 + r;
    offA[i] = row * 128 + ((2 * g) ^ ((r & 3) << 1)) * 16;
  }
  int offW[8];  // w-frag j: row = wn*128+j*16+r, granule g^(r&3)
#pragma unroll
  for (int j = 0; j < 8; ++j) {
    int row = wn * 128 + j * 16 + r;
    offW[j] = row * 64 + (g ^ (r & 3)) * 16;
  }

  f32x4 acc[4][8];
#pragma unroll
  for (int i = 0; i < 4; ++i)
#pragma unroll
    for (int j = 0; j < 8; ++j) acc[i][j] = (f32x4){0.f, 0.f, 0.f, 0.f};

  // prologue: 2 tiles in flight (12 gload_lds/thread outstanding)
  STAGE(0, 0)
  STAGE(1, 1)

#pragma unroll
  for (int kt = 0; kt < NKT; ++kt) {
    // tile kt ready when only tile kt+1's 6 loads remain outstanding
    if (kt < NKT - 1)
      asm volatile("s_waitcnt vmcnt(6)" ::: "memory");
    else
      asm volatile("s_waitcnt vmcnt(0)" ::: "memory");
    __builtin_amdgcn_sched_barrier(0);
    __builtin_amdgcn_s_barrier();  // raw: no compiler vmcnt(0) drain
    __builtin_amdgcn_sched_barrier(0);

    // refill: buf (kt+2)%3 was last read at compute(kt-1); all waves past it
    if (kt < NKT - 2) STAGE((kt + 2) % 3, kt + 2)

    // compute tile kt from buf kt%3
    const int b = kt % 3;
    bf16x8 xa[4];
#pragma unroll
    for (int i = 0; i < 4; ++i) {
      const char* a = smem + AOFF(b) + offA[i];
      float4 lo = *reinterpret_cast<const float4*>(a);
      float4 hi = *reinterpret_cast<const float4*>(a + 16);
      xa[i] = cvt8(lo, hi);
    }
#pragma unroll
    for (int j = 0; j < 8; ++j) {
      bf16x8 wb = *reinterpret_cast<const bf16x8*>(smem + WOFF(b) + offW[j]);
#pragma unroll
      for (int i = 0; i < 4; ++i)
        acc[i][j] = __builtin_amdgcn_mfma_f32_16x16x32_bf16(wb, xa[i],
                                                            acc[i][j], 0, 0, 0);
    }
    // no trailing barrier: next iteration's waitcnt+barrier is the fence
  }

  // ---- epilogue. Swapped operands: D.col(lane&15)=x-row, D.row(quads)=out-col
  // acc[i][j][q] -> Out[m0 + wm*64 + i*16 + r][wn*128 + j*16 + g*4 + q]
#pragma unroll
  for (int i = 0; i < 4; ++i) {
    const size_t rowoff = (m0 + wm * 64 + i * 16 + r) * N_DIM;
#pragma unroll
    for (int j = 0; j < 8; ++j) {
      const int c0 = wn * 128 + j * 16 + g * 4;
      float4 bv = *reinterpret_cast<const float4*>(&bias[c0]);
      float4 o;
      o.x = acc[i][j][0] + bv.x;
      o.y = acc[i][j][1] + bv.y;
      o.z = acc[i][j][2] + bv.z;
      o.w = acc[i][j][3] + bv.w;
      *reinterpret_cast<float4*>(&Out[rowoff + c0]) = o;
    }
  }
#undef STAGE
}

extern "C" void kernel_launch(void* const* d_in, const int* in_sizes, int n_in,
                              void* d_out, int out_size, void* d_ws,
                              size_t ws_size, hipStream_t stream) {
  (void)in_sizes;
  (void)n_in;
  (void)out_size;
  (void)ws_size;
  const float* x = (const float*)d_in[0];
  const float* alpha = (const float*)d_in[1];
  const float* U = (const float*)d_in[2];
  const float* V = (const float*)d_in[3];
  const float* bias = (const float*)d_in[4];
  const int* k_iter = (const int*)d_in[5];
  float* out = (float*)d_out;
  unsigned short* Wb = (unsigned short*)d_ws;  // 512 KiB scratch

  build_w_kernel<<<(N_DIM * K_DIM) / 256, 256, 0, stream>>>(alpha, U, V,
                                                            k_iter, Wb);

  const int lds_bytes = 147456;  // A 3x16KB + W 3x32KB
  hipFuncSetAttribute((const void*)gemm_kernel,
                      hipFuncAttributeMaxDynamicSharedMemorySize, lds_bytes);
  const int grid = M_TOTAL / BM;  // 1024 blocks, each covers all 512 cols
  gemm_kernel<<<grid, 512, lds_bytes, stream>>>(x, Wb, bias, out);
}